// Round 23
// baseline (83.457 us; speedup 1.0000x reference)
//
#include <hip/hip_runtime.h>
#include <hip/hip_bf16.h>
#include <stdint.h>

#define H 128
#define NE 500000
#define NTILES 3907          // ceil(NE/128)
#define GRID 512             // 2 blocks/CU exactly; strided tiles, 7-8 per block
#define TPB 8                // max tiles per block

typedef __bf16 bf16x8 __attribute__((ext_vector_type(8)));
typedef float f32x4 __attribute__((ext_vector_type(4)));

__device__ __forceinline__ float fast_silu(float x) {
    float e = __builtin_amdgcn_exp2f(x * -1.44269504088896341f);
    return x * __builtin_amdgcn_rcpf(1.0f + e);
}

__device__ __forceinline__ unsigned f2bf(float f) {
    unsigned u = __builtin_bit_cast(unsigned, f);
    return (u + 0x7FFFu + ((u >> 16) & 1u)) >> 16;
}

// ---------------------------------------------------------------------------
// Prep: blocks 0..94:  P1[b][c] = emb[b] @ w_lin[0:128][c] + b_lin[c]
//       blocks 95..126: w3t[c][k] = bf16(w_lin[256+k][c]) packed pairs
// ---------------------------------------------------------------------------
__global__ __launch_bounds__(256)
void prep_kernel(const float* __restrict__ emb,
                 const float* __restrict__ w_lin,
                 const float* __restrict__ b_lin,
                 float* __restrict__ P1, float* __restrict__ P2,
                 unsigned* __restrict__ w3t) {
    int b = blockIdx.x, t = threadIdx.x;
    if (b < 95) {
        __shared__ float emb_s[H];
        if (t < H) emb_s[t] = emb[b * H + t];
        __syncthreads();
        int c = t & (H - 1);
        int half = t >> 7;
        const float* wb = w_lin + half * (H * H) + c;
        float a = half ? 0.0f : b_lin[c];
        #pragma unroll 8
        for (int k = 0; k < H; ++k)
            a = fmaf(emb_s[k], wb[k * H], a);
        (half ? P2 : P1)[b * H + c] = a;
    } else {
        int idx = (b - 95) * 256 + t;
        int c = idx >> 6;
        int k = (idx & 63) * 2;
        unsigned lo = f2bf(w_lin[(2 * H + k) * H + c]);
        unsigned hi = f2bf(w_lin[(2 * H + k + 1) * H + c]);
        w3t[idx] = lo | (hi << 16);
    }
}

// ---------------------------------------------------------------------------
// Main: ROUND 23 = r22 (tied champion 82.1us: full-row wave decomposition,
// wave-private transpose epilogue, 3 barriers/tile, NT stores, 64-VGPR razor
// edge) + STRIDED BALANCED GRID: 512 blocks (2/CU exactly), block b handles
// tiles b, b+512, ... (7-8 each). Fixes the 489-block imbalance where 23 CUs
// idled half the kernel and makespan was a full 16 tile-times.
// ---------------------------------------------------------------------------
__global__ __launch_bounds__(512, 4)
void edge_kernel(const float* __restrict__ rbf,
                 const int* __restrict__ ei, const int* __restrict__ ej,
                 const int* __restrict__ xin,
                 const float* __restrict__ w_rbf, const float* __restrict__ b_rbf,
                 const float* __restrict__ P1, const float* __restrict__ P2,
                 const unsigned* __restrict__ w3t,
                 float* __restrict__ out) {
    __shared__ __align__(16) char hs[H * 256];   // h bf16 tile / per-wave staging, 32KB
    __shared__ __align__(16) char wl[H * 256];   // W3^T bf16 swizzled, 32KB
    __shared__ float rbf_s[2][128 * 8];          // 2 x 4KB
    __shared__ int xi_s[2][128];
    __shared__ int xj_s[2][128];

    const int tid = threadIdx.x;
    const int wave = tid >> 6;            // 0..7: owns edges wave*16..+15, all cols
    const int lane = tid & 63;
    const int l15 = lane & 15;
    const int lq = lane >> 4;
    const int er = lane >> 4;             // readout: edge sub-row 0..3
    const int c4g = lane & 15;            // readout: col-group 0..15 (x4 cols)

    const int tile0 = blockIdx.x;         // strided: tiles tile0 + t*GRID
    char* slice = hs + wave * 4096;       // wave-private staging (16x64 f32)

    // ---------------- stage W3^T -> LDS once per block (swizzled) ----------
    #pragma unroll
    for (int it = 0; it < 16; ++it) {
        int idx = tid + it * 512;          // 0..8191 ; row c = idx>>6
        int c = idx >> 6;
        int b4 = (idx & 63) * 4;
        *(unsigned*)(wl + c * 256 + (b4 ^ ((c & 15) << 4))) = w3t[idx];
    }

    // ---------------- pipeline registers ----------------
    float pr0 = 0.f, pr1 = 0.f;           // rbf prefetch
    int pidx = 0;                         // raw node index prefetch

    // ---------------- prologue: load + commit tile0 into buf 0 -------------
    {
        long long gb = (long long)tile0 * 768;
        pr0 = (gb + tid < (long long)NE * 6) ? rbf[gb + tid] : 0.f;
        int d1 = tid + 512;
        pr1 = (d1 < 768 && gb + d1 < (long long)NE * 6) ? rbf[gb + d1] : 0.f;
        int e = tile0 * 128 + (tid & 127);
        if (tid < 128)      pidx = (e < NE) ? ei[e] : 0;
        else if (tid < 256) pidx = (e < NE) ? ej[e] : 0;

        int xg = 0;
        if (tid < 256) xg = xin[pidx];
        rbf_s[0][(tid / 6) * 8 + (tid % 6)] = pr0;
        if (tid + 512 < 768) rbf_s[0][((tid + 512) / 6) * 8 + ((tid + 512) % 6)] = pr1;
        if (tid < 128) xi_s[0][tid] = xg;
        else if (tid < 256) xj_s[0][tid - 128] = xg;
    }

    #pragma unroll 1
    for (int t = 0; t < TPB; ++t) {
        const int tile = tile0 + t * GRID;
        if (tile >= NTILES) break;
        const int buf = t & 1;
        const int ntile = tile + GRID;                 // next strided tile
        const bool hn = (t + 1 < TPB) && (ntile < NTILES);

        // ---- issue next tile's global loads early ----
        if (hn) {
            long long gb = (long long)ntile * 768;
            pr0 = (gb + tid < (long long)NE * 6) ? rbf[gb + tid] : 0.f;
            int d1 = tid + 512;
            pr1 = (d1 < 768 && gb + d1 < (long long)NE * 6) ? rbf[gb + d1] : 0.f;
            int e = ntile * 128 + (tid & 127);
            if (tid < 128)      pidx = (e < NE) ? ei[e] : 0;
            else if (tid < 256) pidx = (e < NE) ? ej[e] : 0;
        }

        __syncthreads();   // (A) commit visible; hs free; NT stores drained

        // ---- h-phase: thread owns 8 cols x 4 edges ----
        {
            const int c8 = (tid & 15) * 8;
            const int eg = tid >> 4;
            f32x4 w0[6], w1[6];
            #pragma unroll
            for (int k = 0; k < 6; ++k) {
                w0[k] = *(const f32x4*)(w_rbf + k * H + c8);
                w1[k] = *(const f32x4*)(w_rbf + k * H + c8 + 4);
            }
            f32x4 b0 = *(const f32x4*)(b_rbf + c8);
            f32x4 b1 = *(const f32x4*)(b_rbf + c8 + 4);

            #pragma unroll
            for (int i = 0; i < 4; ++i) {
                int el = eg * 4 + i;
                f32x4 r03 = *(const f32x4*)(&rbf_s[buf][el * 8]);
                float2 r45 = *(const float2*)(&rbf_s[buf][el * 8 + 4]);
                float rk[6] = {r03[0], r03[1], r03[2], r03[3], r45.x, r45.y};
                f32x4 s0 = b0, s1 = b1;
                #pragma unroll
                for (int k = 0; k < 6; ++k) {
                    s0 += rk[k] * w0[k];
                    s1 += rk[k] * w1[k];
                }
                bf16x8 hv;
                hv[0] = (__bf16)fast_silu(s0[0]);
                hv[1] = (__bf16)fast_silu(s0[1]);
                hv[2] = (__bf16)fast_silu(s0[2]);
                hv[3] = (__bf16)fast_silu(s0[3]);
                hv[4] = (__bf16)fast_silu(s1[0]);
                hv[5] = (__bf16)fast_silu(s1[1]);
                hv[6] = (__bf16)fast_silu(s1[2]);
                hv[7] = (__bf16)fast_silu(s1[3]);
                *(bf16x8*)(hs + el * 256 + ((c8 * 2) ^ ((el & 15) << 4))) = hv;
            }
        }
        __syncthreads();   // (B) hs (h-tile) ready

        // ---- next tile's xin gather: latency hides under MFMA+epilogue ----
        int xg = 0;
        if (hn && tid < 256) xg = xin[pidx];

        // ---- MFMA: wave owns 16 edges (rows wave*16..+15) x all 128 cols ----
        f32x4 acc[8];
        #pragma unroll
        for (int a = 0; a < 8; ++a)
            acc[a] = (f32x4){0.f, 0.f, 0.f, 0.f};

        #pragma unroll
        for (int ks = 0; ks < 4; ++ks) {
            const int kb = ks * 64 + lq * 16;
            const int row = wave * 16 + l15;
            bf16x8 afr = *(const bf16x8*)(hs + row * 256 + (kb ^ ((row & 15) << 4)));
            #pragma unroll
            for (int cf = 0; cf < 8; ++cf) {
                int c = cf * 16 + l15;
                bf16x8 bfr = *(const bf16x8*)(wl + c * 256 + (kb ^ ((c & 15) << 4)));
                acc[cf] = __builtin_amdgcn_mfma_f32_16x16x32_bf16(
                    bfr, afr, acc[cf], 0, 0, 0);
            }
        }
        __syncthreads();   // (C) all hs reads done -> slices reusable

        // ---- wave-private transpose epilogue: two 64-col halves ----
        #pragma unroll
        for (int hf = 0; hf < 2; ++hf) {
            #pragma unroll
            for (int cfl = 0; cfl < 4; ++cfl) {
                int c4 = cfl * 4 + lq;
                *(f32x4*)(slice + ((l15 * 16 + (c4 ^ l15)) << 4)) = acc[hf * 4 + cfl];
            }
            asm volatile("s_waitcnt lgkmcnt(0)" ::: "memory");
            __builtin_amdgcn_sched_barrier(0);

            #pragma unroll
            for (int p = 0; p < 4; ++p) {
                int el = p * 4 + er;                       // 0..15 (wave-local)
                int elg = wave * 16 + el;                  // 0..127 (tile-local)
                int e = tile * 128 + elg;
                f32x4 v = *(const f32x4*)(slice + ((el * 16 + (c4g ^ el)) << 4));
                f32x4 q1 = *(const f32x4*)(P1 + xi_s[buf][elg] * H + hf * 64 + c4g * 4);
                f32x4 q2 = *(const f32x4*)(P2 + xj_s[buf][elg] * H + hf * 64 + c4g * 4);
                f32x4 o;
                #pragma unroll
                for (int r = 0; r < 4; ++r)
                    o[r] = fast_silu(v[r] + q1[r] + q2[r]);
                if (e < NE)
                    __builtin_nontemporal_store(o,
                        (f32x4*)(out + (size_t)e * H + hf * 64 + c4g * 4));
            }
            if (hf == 0) {
                asm volatile("s_waitcnt lgkmcnt(0)" ::: "memory");
                __builtin_amdgcn_sched_barrier(0);
            }
        }

        // ---- commit next tile into the other buffer ----
        if (hn) {
            int nb = buf ^ 1;
            rbf_s[nb][(tid / 6) * 8 + (tid % 6)] = pr0;
            int d1 = tid + 512;
            if (d1 < 768) rbf_s[nb][(d1 / 6) * 8 + (d1 % 6)] = pr1;
            if (tid < 128) xi_s[nb][tid] = xg;
            else if (tid < 256) xj_s[nb][tid - 128] = xg;
        }
    }
}

extern "C" void kernel_launch(void* const* d_in, const int* in_sizes, int n_in,
                              void* d_out, int out_size, void* d_ws, size_t ws_size,
                              hipStream_t stream) {
    const int*   x      = (const int*)d_in[0];
    const float* rbf    = (const float*)d_in[1];
    const int*   ei     = (const int*)d_in[2];
    const int*   ej     = (const int*)d_in[3];
    const float* emb    = (const float*)d_in[4];
    const float* w_rbf  = (const float*)d_in[5];
    const float* b_rbf  = (const float*)d_in[6];
    const float* w_lin  = (const float*)d_in[7];
    const float* b_lin  = (const float*)d_in[8];
    float* out = (float*)d_out;

    float*    P1  = (float*)d_ws;                 // 95*128 f32
    float*    P2  = P1 + 95 * H;                  // 95*128 f32
    unsigned* w3t = (unsigned*)(P2 + 95 * H);     // 128*64 u32 (bf16 pairs)

    prep_kernel<<<95 + 32, 256, 0, stream>>>(emb, w_lin, b_lin, P1, P2, w3t);

    edge_kernel<<<GRID, 512, 0, stream>>>(rbf, ei, ej, x, w_rbf, b_rbf,
                                          P1, P2, w3t, out);
}

// Round 25
// 80.859 us; speedup vs baseline: 1.0321x; 1.0321x over previous
//
#include <hip/hip_runtime.h>
#include <hip/hip_bf16.h>
#include <stdint.h>

#define H 128
#define NE 500000
#define NTILES 3907          // ceil(NE/128)
#define TPB 8                // tiles per block -> 489 blocks (2/CU resident)

typedef __bf16 bf16x8 __attribute__((ext_vector_type(8)));
typedef float f32x4 __attribute__((ext_vector_type(4)));

__device__ __forceinline__ float fast_silu(float x) {
    float e = __builtin_amdgcn_exp2f(x * -1.44269504088896341f);
    return x * __builtin_amdgcn_rcpf(1.0f + e);
}

__device__ __forceinline__ unsigned f2bf(float f) {
    unsigned u = __builtin_bit_cast(unsigned, f);
    return (u + 0x7FFFu + ((u >> 16) & 1u)) >> 16;
}

// ---------------------------------------------------------------------------
// Prep: blocks 0..94:  P1[b][c] = emb[b] @ w_lin[0:128][c] + b_lin[c]
//       blocks 95..126: w3t[c][k] = bf16(w_lin[256+k][c]) packed pairs
// ---------------------------------------------------------------------------
__global__ __launch_bounds__(256)
void prep_kernel(const float* __restrict__ emb,
                 const float* __restrict__ w_lin,
                 const float* __restrict__ b_lin,
                 float* __restrict__ P1, float* __restrict__ P2,
                 unsigned* __restrict__ w3t) {
    int b = blockIdx.x, t = threadIdx.x;
    if (b < 95) {
        __shared__ float emb_s[H];
        if (t < H) emb_s[t] = emb[b * H + t];
        __syncthreads();
        int c = t & (H - 1);
        int half = t >> 7;
        const float* wb = w_lin + half * (H * H) + c;
        float a = half ? 0.0f : b_lin[c];
        #pragma unroll 8
        for (int k = 0; k < H; ++k)
            a = fmaf(emb_s[k], wb[k * H], a);
        (half ? P2 : P1)[b * H + c] = a;
    } else {
        int idx = (b - 95) * 256 + t;
        int c = idx >> 6;
        int k = (idx & 63) * 2;
        unsigned lo = f2bf(w_lin[(2 * H + k) * H + c]);
        unsigned hi = f2bf(w_lin[(2 * H + k + 1) * H + c]);
        w3t[idx] = lo | (hi << 16);
    }
}

// ---------------------------------------------------------------------------
// Main: ROUND 25 = r24 fused h-in-fragment with the bb_s staging bug fixed
// (r24's `else if` branch was unreachable with 512 threads -> bias never
// staged -> garbage h). Lane (l15,lq) of wave w computes its OWN afr
// fragment h[w*16+l15][ks*32+lq*8..+8] in registers; deletes the h-phase,
// its 64KB/tile LDS round trip, and 2 of 3 barriers. ONE barrier per tile
// (A = the single orderly NT-drain point). Epilogue = r22 wave-private
// transpose. (512,4) / 64-VGPR razor edge.
// ---------------------------------------------------------------------------
__global__ __launch_bounds__(512, 4)
void edge_kernel(const float* __restrict__ rbf,
                 const int* __restrict__ ei, const int* __restrict__ ej,
                 const int* __restrict__ xin,
                 const float* __restrict__ w_rbf, const float* __restrict__ b_rbf,
                 const float* __restrict__ P1, const float* __restrict__ P2,
                 const unsigned* __restrict__ w3t,
                 float* __restrict__ out) {
    __shared__ __align__(16) char hs[H * 256];   // per-wave staging slices, 32KB
    __shared__ __align__(16) char wl[H * 256];   // W3^T bf16 swizzled, 32KB
    __shared__ __align__(16) float wr_s[6 * H];  // w_rbf row-major, 3KB
    __shared__ __align__(16) float bb_s[H];      // b_rbf, 0.5KB
    __shared__ float rbf_s[2][128 * 8];          // 2 x 4KB
    __shared__ int xi_s[2][128];
    __shared__ int xj_s[2][128];

    const int tid = threadIdx.x;
    const int wave = tid >> 6;            // 0..7: owns edges wave*16..+15, all cols
    const int lane = tid & 63;
    const int l15 = lane & 15;
    const int lq = lane >> 4;
    const int er = lane >> 4;             // readout: edge sub-row 0..3
    const int c4g = lane & 15;            // readout: col-group 0..15 (x4 cols)

    const int tile0 = blockIdx.x * TPB;
    char* slice = hs + wave * 4096;       // wave-private staging (16x64 f32)

    // ---------------- stage W3^T + w_rbf/b_rbf -> LDS once per block -------
    #pragma unroll
    for (int it = 0; it < 16; ++it) {
        int idx = tid + it * 512;          // 0..8191 ; row c = idx>>6
        int c = idx >> 6;
        int b4 = (idx & 63) * 4;
        *(unsigned*)(wl + c * 256 + (b4 ^ ((c & 15) << 4))) = w3t[idx];
    }
    wr_s[tid] = w_rbf[tid];                            // 0..511
    if (tid < 256) wr_s[tid + 512] = w_rbf[tid + 512]; // 512..767
    if (tid >= 384) bb_s[tid - 384] = b_rbf[tid - 384];// 0..127

    // ---------------- pipeline registers ----------------
    float pr0 = 0.f, pr1 = 0.f;           // rbf prefetch
    int pidx = 0;                         // raw node index prefetch

    // ---------------- prologue: load + commit tile0 into buf 0 -------------
    {
        long long gb = (long long)tile0 * 768;
        pr0 = (gb + tid < (long long)NE * 6) ? rbf[gb + tid] : 0.f;
        int d1 = tid + 512;
        pr1 = (d1 < 768 && gb + d1 < (long long)NE * 6) ? rbf[gb + d1] : 0.f;
        int e = tile0 * 128 + (tid & 127);
        if (tid < 128)      pidx = (e < NE) ? ei[e] : 0;
        else if (tid < 256) pidx = (e < NE) ? ej[e] : 0;

        int xg = 0;
        if (tid < 256) xg = xin[pidx];
        rbf_s[0][(tid / 6) * 8 + (tid % 6)] = pr0;
        if (tid + 512 < 768) rbf_s[0][((tid + 512) / 6) * 8 + ((tid + 512) % 6)] = pr1;
        if (tid < 128) xi_s[0][tid] = xg;
        else if (tid < 256) xj_s[0][tid - 128] = xg;
    }

    #pragma unroll 1
    for (int t = 0; t < TPB; ++t) {
        const int tile = tile0 + t;
        if (tile >= NTILES) break;
        const int buf = t & 1;
        const bool hn = (t + 1 < TPB) && (tile + 1 < NTILES);

        // ---- issue next tile's global loads early ----
        if (hn) {
            long long gb = (long long)(tile + 1) * 768;
            pr0 = (gb + tid < (long long)NE * 6) ? rbf[gb + tid] : 0.f;
            int d1 = tid + 512;
            pr1 = (d1 < 768 && gb + d1 < (long long)NE * 6) ? rbf[gb + d1] : 0.f;
            int e = (tile + 1) * 128 + (tid & 127);
            if (tid < 128)      pidx = (e < NE) ? ei[e] : 0;
            else if (tid < 256) pidx = (e < NE) ? ej[e] : 0;
        }

        __syncthreads();   // (A) the ONLY block barrier: commit visible,
                           //     slices free, prev tile's NT stores drained

        // ---- my rbf row (broadcast LDS read; 6 regs, live all tile) ----
        const int myrow = wave * 16 + l15;
        f32x4 r03 = *(const f32x4*)(&rbf_s[buf][myrow * 8]);
        float2 r45 = *(const float2*)(&rbf_s[buf][myrow * 8 + 4]);
        float rk[6] = {r03[0], r03[1], r03[2], r03[3], r45.x, r45.y};

        // ---- next tile's xin gather: hides under fused compute ----
        int xg = 0;
        if (hn && tid < 256) xg = xin[pidx];

        // ---- fused h+MFMA: per ks compute own afr fragment, then 8 MFMA ----
        f32x4 acc[8];
        #pragma unroll
        for (int a = 0; a < 8; ++a)
            acc[a] = (f32x4){0.f, 0.f, 0.f, 0.f};

        #pragma unroll
        for (int ks = 0; ks < 4; ++ks) {
            const int c0 = ks * 32 + lq * 8;       // my 8 h-cols this ks
            f32x4 sA = *(const f32x4*)(bb_s + c0);
            f32x4 sB = *(const f32x4*)(bb_s + c0 + 4);
            #pragma unroll
            for (int k = 0; k < 6; ++k) {
                f32x4 wA = *(const f32x4*)(wr_s + k * H + c0);
                f32x4 wB = *(const f32x4*)(wr_s + k * H + c0 + 4);
                sA += rk[k] * wA;
                sB += rk[k] * wB;
            }
            bf16x8 afr;
            afr[0] = (__bf16)fast_silu(sA[0]);
            afr[1] = (__bf16)fast_silu(sA[1]);
            afr[2] = (__bf16)fast_silu(sA[2]);
            afr[3] = (__bf16)fast_silu(sA[3]);
            afr[4] = (__bf16)fast_silu(sB[0]);
            afr[5] = (__bf16)fast_silu(sB[1]);
            afr[6] = (__bf16)fast_silu(sB[2]);
            afr[7] = (__bf16)fast_silu(sB[3]);

            const int kb = ks * 64 + lq * 16;
            #pragma unroll
            for (int cf = 0; cf < 8; ++cf) {
                int c = cf * 16 + l15;
                bf16x8 bfr = *(const bf16x8*)(wl + c * 256 + (kb ^ ((c & 15) << 4)));
                acc[cf] = __builtin_amdgcn_mfma_f32_16x16x32_bf16(
                    bfr, afr, acc[cf], 0, 0, 0);
            }
        }

        // ---- wave-private transpose epilogue: two 64-col halves ----
        // slice chunk(el, c4) = el*16 + (c4 ^ el)  (bijective, conflict-free)
        asm volatile("s_waitcnt lgkmcnt(0)" ::: "memory");  // MFMA LDS reads done
        __builtin_amdgcn_sched_barrier(0);
        #pragma unroll
        for (int hf = 0; hf < 2; ++hf) {
            #pragma unroll
            for (int cfl = 0; cfl < 4; ++cfl) {
                int c4 = cfl * 4 + lq;
                *(f32x4*)(slice + ((l15 * 16 + (c4 ^ l15)) << 4)) = acc[hf * 4 + cfl];
            }
            asm volatile("s_waitcnt lgkmcnt(0)" ::: "memory");
            __builtin_amdgcn_sched_barrier(0);

            #pragma unroll
            for (int p = 0; p < 4; ++p) {
                int el = p * 4 + er;                       // 0..15 (wave-local)
                int elg = wave * 16 + el;                  // 0..127 (tile-local)
                int e = tile * 128 + elg;
                f32x4 v = *(const f32x4*)(slice + ((el * 16 + (c4g ^ el)) << 4));
                f32x4 q1 = *(const f32x4*)(P1 + xi_s[buf][elg] * H + hf * 64 + c4g * 4);
                f32x4 q2 = *(const f32x4*)(P2 + xj_s[buf][elg] * H + hf * 64 + c4g * 4);
                f32x4 o;
                #pragma unroll
                for (int r = 0; r < 4; ++r)
                    o[r] = fast_silu(v[r] + q1[r] + q2[r]);
                if (e < NE)
                    __builtin_nontemporal_store(o,
                        (f32x4*)(out + (size_t)e * H + hf * 64 + c4g * 4));
            }
            if (hf == 0) {
                asm volatile("s_waitcnt lgkmcnt(0)" ::: "memory");
                __builtin_amdgcn_sched_barrier(0);
            }
        }

        // ---- commit next tile into the other buffer ----
        if (hn) {
            int nb = buf ^ 1;
            rbf_s[nb][(tid / 6) * 8 + (tid % 6)] = pr0;
            int d1 = tid + 512;
            if (d1 < 768) rbf_s[nb][(d1 / 6) * 8 + (d1 % 6)] = pr1;
            if (tid < 128) xi_s[nb][tid] = xg;
            else if (tid < 256) xj_s[nb][tid - 128] = xg;
        }
    }
}

extern "C" void kernel_launch(void* const* d_in, const int* in_sizes, int n_in,
                              void* d_out, int out_size, void* d_ws, size_t ws_size,
                              hipStream_t stream) {
    const int*   x      = (const int*)d_in[0];
    const float* rbf    = (const float*)d_in[1];
    const int*   ei     = (const int*)d_in[2];
    const int*   ej     = (const int*)d_in[3];
    const float* emb    = (const float*)d_in[4];
    const float* w_rbf  = (const float*)d_in[5];
    const float* b_rbf  = (const float*)d_in[6];
    const float* w_lin  = (const float*)d_in[7];
    const float* b_lin  = (const float*)d_in[8];
    float* out = (float*)d_out;

    float*    P1  = (float*)d_ws;                 // 95*128 f32
    float*    P2  = P1 + 95 * H;                  // 95*128 f32
    unsigned* w3t = (unsigned*)(P2 + 95 * H);     // 128*64 u32 (bf16 pairs)

    prep_kernel<<<95 + 32, 256, 0, stream>>>(emb, w_lin, b_lin, P1, P2, w3t);

    int nblk = (NTILES + TPB - 1) / TPB;          // 489
    edge_kernel<<<nblk, 512, 0, stream>>>(rbf, ei, ej, x, w_rbf, b_rbf,
                                          P1, P2, w3t, out);
}

// Round 26
// 80.690 us; speedup vs baseline: 1.0343x; 1.0021x over previous
//
#include <hip/hip_runtime.h>
#include <hip/hip_bf16.h>
#include <stdint.h>

#define H 128
#define NE 500000
#define NTILES 3907          // ceil(NE/128)
#define TPB 8                // tiles per block -> 489 blocks (2/CU resident)

typedef __bf16 bf16x8 __attribute__((ext_vector_type(8)));
typedef float f32x4 __attribute__((ext_vector_type(4)));

__device__ __forceinline__ float fast_silu(float x) {
    float e = __builtin_amdgcn_exp2f(x * -1.44269504088896341f);
    return x * __builtin_amdgcn_rcpf(1.0f + e);
}

__device__ __forceinline__ unsigned f2bf(float f) {
    unsigned u = __builtin_bit_cast(unsigned, f);
    return (u + 0x7FFFu + ((u >> 16) & 1u)) >> 16;
}

// ---------------------------------------------------------------------------
// Prep v2 (ROUND 26): P-blocks gain 4x K-parallelism. Thread (cg,half,kq)
// accumulates a f32x4 over its 32-element K-quarter (4 load-batches vs 16 ->
// ~4x shorter latency chain), then a 4-way LDS reduce. w3t blocks unchanged.
//   blocks 0..94:   P1[b] = emb[b] @ w_lin[0:128] + b_lin ; P2 likewise
//   blocks 95..126: w3t[c][k] = bf16(w_lin[256+k][c]) packed pairs
// ---------------------------------------------------------------------------
__global__ __launch_bounds__(256)
void prep_kernel(const float* __restrict__ emb,
                 const float* __restrict__ w_lin,
                 const float* __restrict__ b_lin,
                 float* __restrict__ P1, float* __restrict__ P2,
                 unsigned* __restrict__ w3t) {
    int b = blockIdx.x, t = threadIdx.x;
    if (b < 95) {
        __shared__ float emb_s[H];
        __shared__ f32x4 part[256];
        if (t < H) emb_s[t] = emb[b * H + t];
        __syncthreads();
        const int cg = t & 31;            // 4-col group: cols cg*4..+3
        const int half = (t >> 5) & 1;    // 0 -> P1, 1 -> P2
        const int kq = t >> 6;            // K quarter: k = kq*32..+31
        const float* wb = w_lin + half * (H * H);
        f32x4 a = {0.f, 0.f, 0.f, 0.f};
        #pragma unroll 8
        for (int k = kq * 32; k < kq * 32 + 32; ++k) {
            f32x4 w4 = *(const f32x4*)(wb + k * H + cg * 4);
            a += emb_s[k] * w4;
        }
        part[t] = a;
        __syncthreads();
        if (kq == 0) {
            f32x4 s = part[t] + part[t + 64] + part[t + 128] + part[t + 192];
            int c = cg * 4;
            if (half == 0) {
                s += *(const f32x4*)(b_lin + c);
                *(f32x4*)(P1 + b * H + c) = s;
            } else {
                *(f32x4*)(P2 + b * H + c) = s;
            }
        }
    } else {
        int idx = (b - 95) * 256 + t;
        int c = idx >> 6;
        int k = (idx & 63) * 2;
        unsigned lo = f2bf(w_lin[(2 * H + k) * H + c]);
        unsigned hi = f2bf(w_lin[(2 * H + k + 1) * H + c]);
        w3t[idx] = lo | (hi << 16);
    }
}

// ---------------------------------------------------------------------------
// Main: byte-identical to r25 champion (80.9us): fused h-in-fragment (lane
// computes its own afr fragment in regs; no h-phase, no h-LDS round trip),
// ONE barrier per tile (A = single orderly NT-drain point), wave-private
// transpose epilogue, (512,4) / 64-VGPR razor edge.
// ---------------------------------------------------------------------------
__global__ __launch_bounds__(512, 4)
void edge_kernel(const float* __restrict__ rbf,
                 const int* __restrict__ ei, const int* __restrict__ ej,
                 const int* __restrict__ xin,
                 const float* __restrict__ w_rbf, const float* __restrict__ b_rbf,
                 const float* __restrict__ P1, const float* __restrict__ P2,
                 const unsigned* __restrict__ w3t,
                 float* __restrict__ out) {
    __shared__ __align__(16) char hs[H * 256];   // per-wave staging slices, 32KB
    __shared__ __align__(16) char wl[H * 256];   // W3^T bf16 swizzled, 32KB
    __shared__ __align__(16) float wr_s[6 * H];  // w_rbf row-major, 3KB
    __shared__ __align__(16) float bb_s[H];      // b_rbf, 0.5KB
    __shared__ float rbf_s[2][128 * 8];          // 2 x 4KB
    __shared__ int xi_s[2][128];
    __shared__ int xj_s[2][128];

    const int tid = threadIdx.x;
    const int wave = tid >> 6;            // 0..7: owns edges wave*16..+15, all cols
    const int lane = tid & 63;
    const int l15 = lane & 15;
    const int lq = lane >> 4;
    const int er = lane >> 4;             // readout: edge sub-row 0..3
    const int c4g = lane & 15;            // readout: col-group 0..15 (x4 cols)

    const int tile0 = blockIdx.x * TPB;
    char* slice = hs + wave * 4096;       // wave-private staging (16x64 f32)

    // ---------------- stage W3^T + w_rbf/b_rbf -> LDS once per block -------
    #pragma unroll
    for (int it = 0; it < 16; ++it) {
        int idx = tid + it * 512;          // 0..8191 ; row c = idx>>6
        int c = idx >> 6;
        int b4 = (idx & 63) * 4;
        *(unsigned*)(wl + c * 256 + (b4 ^ ((c & 15) << 4))) = w3t[idx];
    }
    wr_s[tid] = w_rbf[tid];                            // 0..511
    if (tid < 256) wr_s[tid + 512] = w_rbf[tid + 512]; // 512..767
    if (tid >= 384) bb_s[tid - 384] = b_rbf[tid - 384];// 0..127

    // ---------------- pipeline registers ----------------
    float pr0 = 0.f, pr1 = 0.f;           // rbf prefetch
    int pidx = 0;                         // raw node index prefetch

    // ---------------- prologue: load + commit tile0 into buf 0 -------------
    {
        long long gb = (long long)tile0 * 768;
        pr0 = (gb + tid < (long long)NE * 6) ? rbf[gb + tid] : 0.f;
        int d1 = tid + 512;
        pr1 = (d1 < 768 && gb + d1 < (long long)NE * 6) ? rbf[gb + d1] : 0.f;
        int e = tile0 * 128 + (tid & 127);
        if (tid < 128)      pidx = (e < NE) ? ei[e] : 0;
        else if (tid < 256) pidx = (e < NE) ? ej[e] : 0;

        int xg = 0;
        if (tid < 256) xg = xin[pidx];
        rbf_s[0][(tid / 6) * 8 + (tid % 6)] = pr0;
        if (tid + 512 < 768) rbf_s[0][((tid + 512) / 6) * 8 + ((tid + 512) % 6)] = pr1;
        if (tid < 128) xi_s[0][tid] = xg;
        else if (tid < 256) xj_s[0][tid - 128] = xg;
    }

    #pragma unroll 1
    for (int t = 0; t < TPB; ++t) {
        const int tile = tile0 + t;
        if (tile >= NTILES) break;
        const int buf = t & 1;
        const bool hn = (t + 1 < TPB) && (tile + 1 < NTILES);

        // ---- issue next tile's global loads early ----
        if (hn) {
            long long gb = (long long)(tile + 1) * 768;
            pr0 = (gb + tid < (long long)NE * 6) ? rbf[gb + tid] : 0.f;
            int d1 = tid + 512;
            pr1 = (d1 < 768 && gb + d1 < (long long)NE * 6) ? rbf[gb + d1] : 0.f;
            int e = (tile + 1) * 128 + (tid & 127);
            if (tid < 128)      pidx = (e < NE) ? ei[e] : 0;
            else if (tid < 256) pidx = (e < NE) ? ej[e] : 0;
        }

        __syncthreads();   // (A) the ONLY block barrier: commit visible,
                           //     slices free, prev tile's NT stores drained

        // ---- my rbf row (broadcast LDS read; 6 regs, live all tile) ----
        const int myrow = wave * 16 + l15;
        f32x4 r03 = *(const f32x4*)(&rbf_s[buf][myrow * 8]);
        float2 r45 = *(const float2*)(&rbf_s[buf][myrow * 8 + 4]);
        float rk[6] = {r03[0], r03[1], r03[2], r03[3], r45.x, r45.y};

        // ---- next tile's xin gather: hides under fused compute ----
        int xg = 0;
        if (hn && tid < 256) xg = xin[pidx];

        // ---- fused h+MFMA: per ks compute own afr fragment, then 8 MFMA ----
        f32x4 acc[8];
        #pragma unroll
        for (int a = 0; a < 8; ++a)
            acc[a] = (f32x4){0.f, 0.f, 0.f, 0.f};

        #pragma unroll
        for (int ks = 0; ks < 4; ++ks) {
            const int c0 = ks * 32 + lq * 8;       // my 8 h-cols this ks
            f32x4 sA = *(const f32x4*)(bb_s + c0);
            f32x4 sB = *(const f32x4*)(bb_s + c0 + 4);
            #pragma unroll
            for (int k = 0; k < 6; ++k) {
                f32x4 wA = *(const f32x4*)(wr_s + k * H + c0);
                f32x4 wB = *(const f32x4*)(wr_s + k * H + c0 + 4);
                sA += rk[k] * wA;
                sB += rk[k] * wB;
            }
            bf16x8 afr;
            afr[0] = (__bf16)fast_silu(sA[0]);
            afr[1] = (__bf16)fast_silu(sA[1]);
            afr[2] = (__bf16)fast_silu(sA[2]);
            afr[3] = (__bf16)fast_silu(sA[3]);
            afr[4] = (__bf16)fast_silu(sB[0]);
            afr[5] = (__bf16)fast_silu(sB[1]);
            afr[6] = (__bf16)fast_silu(sB[2]);
            afr[7] = (__bf16)fast_silu(sB[3]);

            const int kb = ks * 64 + lq * 16;
            #pragma unroll
            for (int cf = 0; cf < 8; ++cf) {
                int c = cf * 16 + l15;
                bf16x8 bfr = *(const bf16x8*)(wl + c * 256 + (kb ^ ((c & 15) << 4)));
                acc[cf] = __builtin_amdgcn_mfma_f32_16x16x32_bf16(
                    bfr, afr, acc[cf], 0, 0, 0);
            }
        }

        // ---- wave-private transpose epilogue: two 64-col halves ----
        // slice chunk(el, c4) = el*16 + (c4 ^ el)  (bijective, conflict-free)
        asm volatile("s_waitcnt lgkmcnt(0)" ::: "memory");  // MFMA LDS reads done
        __builtin_amdgcn_sched_barrier(0);
        #pragma unroll
        for (int hf = 0; hf < 2; ++hf) {
            #pragma unroll
            for (int cfl = 0; cfl < 4; ++cfl) {
                int c4 = cfl * 4 + lq;
                *(f32x4*)(slice + ((l15 * 16 + (c4 ^ l15)) << 4)) = acc[hf * 4 + cfl];
            }
            asm volatile("s_waitcnt lgkmcnt(0)" ::: "memory");
            __builtin_amdgcn_sched_barrier(0);

            #pragma unroll
            for (int p = 0; p < 4; ++p) {
                int el = p * 4 + er;                       // 0..15 (wave-local)
                int elg = wave * 16 + el;                  // 0..127 (tile-local)
                int e = tile * 128 + elg;
                f32x4 v = *(const f32x4*)(slice + ((el * 16 + (c4g ^ el)) << 4));
                f32x4 q1 = *(const f32x4*)(P1 + xi_s[buf][elg] * H + hf * 64 + c4g * 4);
                f32x4 q2 = *(const f32x4*)(P2 + xj_s[buf][elg] * H + hf * 64 + c4g * 4);
                f32x4 o;
                #pragma unroll
                for (int r = 0; r < 4; ++r)
                    o[r] = fast_silu(v[r] + q1[r] + q2[r]);
                if (e < NE)
                    __builtin_nontemporal_store(o,
                        (f32x4*)(out + (size_t)e * H + hf * 64 + c4g * 4));
            }
            if (hf == 0) {
                asm volatile("s_waitcnt lgkmcnt(0)" ::: "memory");
                __builtin_amdgcn_sched_barrier(0);
            }
        }

        // ---- commit next tile into the other buffer ----
        if (hn) {
            int nb = buf ^ 1;
            rbf_s[nb][(tid / 6) * 8 + (tid % 6)] = pr0;
            int d1 = tid + 512;
            if (d1 < 768) rbf_s[nb][(d1 / 6) * 8 + (d1 % 6)] = pr1;
            if (tid < 128) xi_s[nb][tid] = xg;
            else if (tid < 256) xj_s[nb][tid - 128] = xg;
        }
    }
}

extern "C" void kernel_launch(void* const* d_in, const int* in_sizes, int n_in,
                              void* d_out, int out_size, void* d_ws, size_t ws_size,
                              hipStream_t stream) {
    const int*   x      = (const int*)d_in[0];
    const float* rbf    = (const float*)d_in[1];
    const int*   ei     = (const int*)d_in[2];
    const int*   ej     = (const int*)d_in[3];
    const float* emb    = (const float*)d_in[4];
    const float* w_rbf  = (const float*)d_in[5];
    const float* b_rbf  = (const float*)d_in[6];
    const float* w_lin  = (const float*)d_in[7];
    const float* b_lin  = (const float*)d_in[8];
    float* out = (float*)d_out;

    float*    P1  = (float*)d_ws;                 // 95*128 f32
    float*    P2  = P1 + 95 * H;                  // 95*128 f32
    unsigned* w3t = (unsigned*)(P2 + 95 * H);     // 128*64 u32 (bf16 pairs)

    prep_kernel<<<95 + 32, 256, 0, stream>>>(emb, w_lin, b_lin, P1, P2, w3t);

    int nblk = (NTILES + TPB - 1) / TPB;          // 489
    edge_kernel<<<nblk, 512, 0, stream>>>(rbf, ei, ej, x, w_rbf, b_rbf,
                                          P1, P2, w3t, out);
}